// Round 15
// baseline (129.140 us; speedup 1.0000x reference)
//
#include <hip/hip_runtime.h>
#include <hip/hip_bf16.h>
#if __has_include(<hip/hip_fp8.h>)
#include <hip/hip_fp8.h>
#define HAVE_HIP_FP8 1
#endif

typedef __hip_bfloat16 bf16;
typedef __attribute__((ext_vector_type(8))) short short8;
typedef __attribute__((ext_vector_type(4))) float float4v;
typedef __attribute__((ext_vector_type(2))) unsigned int uint2v;

static constexpr int NN = 4096;   // D*H*W
static constexpr int CC = 64;     // channels
static constexpr int BB = 2;      // batch
static constexpr int WV = 16;     // waves per attn block (j-split)

// ---------- dtype helpers ----------
template <typename T> __device__ __forceinline__ float cvt_in(T v);
template <> __device__ __forceinline__ float cvt_in<float>(float v) { return v; }
template <> __device__ __forceinline__ float cvt_in<bf16>(bf16 v) { return __bfloat162float(v); }

__device__ __forceinline__ unsigned int f2b(float f) {
    return (unsigned int)__builtin_bit_cast(unsigned short, __float2bfloat16(f));
}

// pack two floats into fp8-e4m3 pair within `old`; HI selects half-word.
// word_sel of the builtin must be an immediate -> template parameter (R13).
template <bool HI>
__device__ __forceinline__ unsigned int pk2_fp8(float a, float b, unsigned int old)
{
#if defined(__has_builtin) && __has_builtin(__builtin_amdgcn_cvt_pk_fp8_f32)
    return (unsigned int)__builtin_amdgcn_cvt_pk_fp8_f32(a, b, (int)old, HI);
#elif defined(HAVE_HIP_FP8)
    unsigned int v = (unsigned int)__hip_fp8_e4m3(a).__x |
                     ((unsigned int)__hip_fp8_e4m3(b).__x << 8);
    return HI ? ((old & 0x0000FFFFu) | (v << 16))
              : ((old & 0xFFFF0000u) | v);
#else
#error "no fp8 conversion path available"
#endif
}

__device__ __forceinline__ unsigned char f2fp8b(float a) {
    return (unsigned char)(pk2_fp8<false>(a, 0.f, 0u) & 0xFFu);
}

// ---------- per-block dtype detect (first 1024 bf16 slots of x) ----------
__device__ __forceinline__ int block_detect_bf16(const void* x, float* sred) {
    const bf16* xb = (const bf16*)x;
    float mx = 0.f;
    for (int t = threadIdx.x; t < 1024; t += blockDim.x) {
        float a = fabsf(__bfloat162float(xb[t]));
        if (!(a < 1e30f)) a = 1e30f;   // NaN/Inf clamp
        mx = fmaxf(mx, a);
    }
#pragma unroll
    for (int off = 32; off; off >>= 1) mx = fmaxf(mx, __shfl_xor(mx, off));
    const int nw = blockDim.x >> 6;
    if ((threadIdx.x & 63) == 0) sred[threadIdx.x >> 6] = mx;
    __syncthreads();
    float m = 0.f;
    for (int wv = 0; wv < nw; ++wv) m = fmaxf(m, sred[wv]);
    return m < 1000.f ? 1 : 0;
}

// ---------- kernel 1: projections (4-way c-split, R11) ----------
// qT/kT: j-major bf16 [b][n][d] (16B rows, MFMA-frag ready).
// vfrag (fp8 e4m3): fragment-major V. Tile = (jblk=j>>5, cs=c>>4),
// 512 BYTES: in-tile byte = ((j>>3)&3)*128 + (c&15)*8 + (j&7); attn A-frag
// load = tile*512 + lane*8 (8B/lane dwordx2, coalesced 512B/instr).
template <typename TIO>
__device__ __forceinline__ void proj_body(
    const TIO* __restrict__ x,
    const TIO* __restrict__ Wq, const TIO* __restrict__ bq,
    const TIO* __restrict__ Wk, const TIO* __restrict__ bk,
    const TIO* __restrict__ Wv, const TIO* __restrict__ bv,
    unsigned short* __restrict__ qT, unsigned short* __restrict__ kT,
    unsigned char* __restrict__ vfrag, float* sW, float* sb, float* part)
{
    const int tid  = threadIdx.x;
    const int colq = tid & 63;                   // column within block
    const int cq   = tid >> 6;                   // c-quarter (wave) 0..3
    const int col  = blockIdx.x * 64 + colq;     // 0..B*NN-1
    const int b    = col >> 12;
    const int n    = col & (NN - 1);
    const int og   = blockIdx.y;                 // 0 => q+k, 1..4 => v

    if (og == 0) {
        for (int t = tid; t < 1024; t += 256) {
            int r = t >> 6, c = t & 63;
            sW[t] = cvt_in<TIO>(r < 8 ? Wq[r * 64 + c] : Wk[(r - 8) * 64 + c]);
        }
        if (tid < 16)
            sb[tid] = cvt_in<TIO>(tid < 8 ? bq[tid] : bk[tid - 8]);
    } else {
        const int r0 = (og - 1) * 16;
        for (int t = tid; t < 1024; t += 256)
            sW[t] = cvt_in<TIO>(Wv[(r0 + (t >> 6)) * 64 + (t & 63)]);
        if (tid < 16)
            sb[tid] = cvt_in<TIO>(bv[r0 + tid]);
    }
    __syncthreads();

    float xv[16];
    const TIO* xb = x + ((size_t)b * CC + cq * 16) * NN + n;
#pragma unroll
    for (int c = 0; c < 16; ++c) xv[c] = cvt_in<TIO>(xb[(size_t)c * NN]);

    float acc[16];
#pragma unroll
    for (int o = 0; o < 16; ++o) {
        float a = 0.f;
#pragma unroll
        for (int c = 0; c < 16; ++c)
            a = fmaf(sW[o * 64 + cq * 16 + c], xv[c], a);
        acc[o] = a;
    }

    if (cq > 0) {
#pragma unroll
        for (int o = 0; o < 16; ++o)
            part[((cq - 1) * 16 + o) * 64 + colq] = acc[o];
    }
    __syncthreads();
    if (cq != 0) return;

#pragma unroll
    for (int o = 0; o < 16; ++o)
        acc[o] += sb[o] + part[o * 64 + colq] + part[(16 + o) * 64 + colq] +
                  part[(32 + o) * 64 + colq];

    if (og == 0) {
        unsigned short row[16];
#pragma unroll
        for (int o = 0; o < 16; ++o) row[o] = (unsigned short)f2b(acc[o]);
        *(short8*)(qT + (size_t)(b * NN + n) * 8) = *(const short8*)&row[0];
        *(short8*)(kT + (size_t)(b * NN + n) * 8) = *(const short8*)&row[8];
    } else {
        unsigned char* vt = vfrag +
            (size_t)((b * 128 + (n >> 5)) * 4 + (og - 1)) * 512 +
            ((n >> 3) & 3) * 128 + (n & 7);
#pragma unroll
        for (int o = 0; o < 16; ++o)
            vt[o * 8] = f2fp8b(acc[o]);
    }
}

__global__ __launch_bounds__(256) void proj_kernel(
    const void* x, const void* Wq, const void* bq, const void* Wk,
    const void* bk, const void* Wv, const void* bv,
    unsigned short* qT, unsigned short* kT, unsigned char* vfrag)
{
    __shared__ float sW[16 * 64];
    __shared__ float sb[16];
    __shared__ float part[3 * 16 * 64];
    __shared__ float sred[4];
    const int bf = block_detect_bf16(x, sred);
    __syncthreads();
    if (bf)
        proj_body<bf16>((const bf16*)x, (const bf16*)Wq, (const bf16*)bq,
                        (const bf16*)Wk, (const bf16*)bk, (const bf16*)Wv,
                        (const bf16*)bv, qT, kT, vfrag, sW, sb, part);
    else
        proj_body<float>((const float*)x, (const float*)Wq, (const float*)bq,
                         (const float*)Wk, (const float*)bk, (const float*)Wv,
                         (const float*)bv, qT, kT, vfrag, sW, sb, part);
}

// ---------- kernel 2: fused flash attention — shuffle-free + fp8 PV + dbuf ----------
// Block = 1024 thr = 16 waves, one block per 16 queries, grid 512,
// launch_bounds (1024,8): 64-VGPR cap -> 2 blocks/CU, one residency round.
// kf rows j-PERMUTED (R12): S^T MFMA #1 row r ↦ j=(r>>2)*8+(r&3), #2 ↦ +4,
// so lane(q,m)'s 8 exp'd S values are exactly the K=32 B-frag layout
// (k=q*8+e) — zero cross-lane ops. PV runs fp8_fp8 (R13/R14): half V bytes.
// R15: fp8 halved vf regs (16->8/unit), so R8's 2-deep register double-
// buffer fits back under the 64-cap: AttnUnit = 16 regs, two in flight +
// acc 16 + qf 4 + misc ~ 60.
struct AttnUnit {
    short8 kf1, kf2;    // 8 VGPRs (quads 1-3 zero)
    uint2v vf[4];       // 8 VGPRs (fp8)
};

__device__ __forceinline__ void load_unit(
    const unsigned short* __restrict__ kTb,
    const unsigned char* __restrict__ vfb,
    int j0, int quad, int jperm, int lane, AttnUnit& U)
{
    const short8 zero8 = {};
    U.kf1 = zero8;
    U.kf2 = zero8;
    if (quad == 0) {
        const unsigned short* kp = kTb + (size_t)(j0 + jperm) * 8;
        U.kf1 = *(const short8*)kp;          // rows -> j = q*8 + r
        U.kf2 = *(const short8*)(kp + 32);   // rows -> j = q*8 + 4 + r
    }
    const unsigned char* vt = vfb + (size_t)(j0 >> 5) * 4 * 512 + lane * 8;
#pragma unroll
    for (int cs = 0; cs < 4; ++cs)
        U.vf[cs] = *(const uint2v*)(vt + cs * 512);
}

__device__ __forceinline__ void compute_unit(
    const AttnUnit& U, const short8& qf, float4v acc[4], float& lsum)
{
    const float4v zero4 = {0.f, 0.f, 0.f, 0.f};
    const float4v st1 =
        __builtin_amdgcn_mfma_f32_16x16x32_bf16(U.kf1, qf, zero4, 0, 0, 0);
    const float4v st2 =
        __builtin_amdgcn_mfma_f32_16x16x32_bf16(U.kf2, qf, zero4, 0, 0, 0);

    const float e0 = __expf(st1[0]), e1 = __expf(st1[1]);
    const float e2 = __expf(st1[2]), e3 = __expf(st1[3]);
    const float f0 = __expf(st2[0]), f1 = __expf(st2[1]);
    const float f2 = __expf(st2[2]), f3 = __expf(st2[3]);
    lsum += ((e0 + e1) + (e2 + e3)) + ((f0 + f1) + (f2 + f3));

    // B-frag fp8: byte e ↔ k = q*8+e: [e0..e3, f0..f3]
    uint2v pw;
    pw.x = pk2_fp8<true>(e2, e3, pk2_fp8<false>(e0, e1, 0u));
    pw.y = pk2_fp8<true>(f2, f3, pk2_fp8<false>(f0, f1, 0u));
    const long long pb = __builtin_bit_cast(long long, pw);

#pragma unroll
    for (int cs = 0; cs < 4; ++cs)
        acc[cs] = __builtin_amdgcn_mfma_f32_16x16x32_fp8_fp8(
            __builtin_bit_cast(long long, U.vf[cs]), pb, acc[cs], 0, 0, 0);
}

__global__ __launch_bounds__(1024, 8) void attn_kernel(
    const unsigned short* __restrict__ qT, const unsigned short* __restrict__ kT,
    const unsigned char* __restrict__ vfrag,
    const void* __restrict__ xv, const void* __restrict__ gammav, void* outv)
{
    __shared__ float redpool[WV * 1024];   // 64 KB cross-wave acc reduce
    __shared__ float lpart[WV][16];
    __shared__ float sred[WV];

    const int bf = block_detect_bf16(xv, sred);

    const int w    = threadIdx.x >> 6;
    const int lane = threadIdx.x & 63;
    const int m    = lane & 15;
    const int quad = lane >> 4;
    const int b    = blockIdx.x >> 8;
    const int i0   = (blockIdx.x & 255) << 4;

    const short8  zero8 = {};
    const float4v zero4 = {0.f, 0.f, 0.f, 0.f};

    short8 qf = zero8;
    if (quad == 0)
        qf = *(const short8*)(qT + (size_t)(b * NN + i0 + m) * 8);

    float4v acc[4] = {zero4, zero4, zero4, zero4};
    float lsum = 0.f;

    const unsigned short* kTb = kT + (size_t)b * NN * 8;
    const unsigned char*  vfb = vfrag + (size_t)b * CC * NN;

    // permuted j for S rows: row r -> j = (r>>2)*8 + (r&3)
    const int jperm = ((m >> 2) << 3) + (m & 3);
    const int jbase = w * (NN / WV);

    AttnUnit A, B;
    load_unit(kTb, vfb, jbase, quad, jperm, lane, A);
#pragma unroll
    for (int u = 0; u < 8; u += 2) {
        load_unit(kTb, vfb, jbase + (u + 1) * 32, quad, jperm, lane, B);
        compute_unit(A, qf, acc, lsum);
        if (u + 2 < 8)
            load_unit(kTb, vfb, jbase + (u + 2) * 32, quad, jperm, lane, A);
        compute_unit(B, qf, acc, lsum);
    }

    // ---- rowsum: lane's partial covers i=m; reduce across quads ----
    lsum += __shfl_xor(lsum, 16);
    lsum += __shfl_xor(lsum, 32);
    if (lane < 16) lpart[w][lane] = lsum;

    // ---- partial accs -> LDS ----
    float* redw = redpool + w * 1024;
#pragma unroll
    for (int cs = 0; cs < 4; ++cs)
#pragma unroll
        for (int r = 0; r < 4; ++r)
            redw[(cs * 4 + r) * 64 + lane] = acc[cs][r];
    __syncthreads();

    // ---- wave w finalizes t = w: c = (t>>2)*16 + quad*4 + (t&3), i = i0+m ----
    float lt = 0.f;
#pragma unroll
    for (int wv = 0; wv < WV; ++wv) lt += lpart[wv][m];
    const float linv = 1.f / lt;

    float v = 0.f;
#pragma unroll
    for (int wv = 0; wv < WV; ++wv) v += redpool[wv * 1024 + w * 64 + lane];

    const int c  = (w >> 2) * 16 + quad * 4 + (w & 3);
    const int ig = i0 + m;
    const size_t off = ((size_t)b * CC + c) * NN + ig;

    if (bf) {
        const float gl = __bfloat162float(((const bf16*)gammav)[0]) * linv;
        ((bf16*)outv)[off] = __float2bfloat16(
            fmaf(gl, v, __bfloat162float(((const bf16*)xv)[off])));
    } else {
        const float gl = ((const float*)gammav)[0] * linv;
        ((float*)outv)[off] = fmaf(gl, v, ((const float*)xv)[off]);
    }
}

extern "C" void kernel_launch(void* const* d_in, const int* in_sizes, int n_in,
                              void* d_out, int out_size, void* d_ws, size_t ws_size,
                              hipStream_t stream)
{
    const void* x     = d_in[0];
    const void* Wq    = d_in[1];
    const void* bq    = d_in[2];
    const void* Wk    = d_in[3];
    const void* bk    = d_in[4];
    const void* Wv    = d_in[5];
    const void* bv    = d_in[6];
    const void* gamma = d_in[7];

    // workspace: qT | kT (bf16-as-ushort) | vfrag (fp8 bytes)
    unsigned short* qT    = (unsigned short*)d_ws;
    unsigned short* kT    = qT + (size_t)BB * NN * 8;
    unsigned char*  vfrag = (unsigned char*)(kT + (size_t)BB * NN * 8);

    proj_kernel<<<dim3(BB * NN / 64, 5), 256, 0, stream>>>(
        x, Wq, bq, Wk, bk, Wv, bv, qT, kT, vfrag);
    attn_kernel<<<BB * (NN / 16), 1024, 0, stream>>>(
        qT, kT, vfrag, x, gamma, d_out);
}

// Round 16
// 91.881 us; speedup vs baseline: 1.4055x; 1.4055x over previous
//
#include <hip/hip_runtime.h>
#include <hip/hip_bf16.h>
#if __has_include(<hip/hip_fp8.h>)
#include <hip/hip_fp8.h>
#define HAVE_HIP_FP8 1
#endif

typedef __hip_bfloat16 bf16;
typedef __attribute__((ext_vector_type(8))) short short8;
typedef __attribute__((ext_vector_type(4))) float float4v;
typedef __attribute__((ext_vector_type(2))) unsigned int uint2v;

static constexpr int NN = 4096;   // D*H*W
static constexpr int CC = 64;     // channels
static constexpr int BB = 2;      // batch
static constexpr int WV = 16;     // waves per attn block (j-split)

// ---------- dtype helpers ----------
template <typename T> __device__ __forceinline__ float cvt_in(T v);
template <> __device__ __forceinline__ float cvt_in<float>(float v) { return v; }
template <> __device__ __forceinline__ float cvt_in<bf16>(bf16 v) { return __bfloat162float(v); }

__device__ __forceinline__ unsigned int f2b(float f) {
    return (unsigned int)__builtin_bit_cast(unsigned short, __float2bfloat16(f));
}

// pack two floats into fp8-e4m3 pair within `old`; HI selects half-word.
// word_sel of the builtin must be an immediate -> template parameter (R13).
template <bool HI>
__device__ __forceinline__ unsigned int pk2_fp8(float a, float b, unsigned int old)
{
#if defined(__has_builtin) && __has_builtin(__builtin_amdgcn_cvt_pk_fp8_f32)
    return (unsigned int)__builtin_amdgcn_cvt_pk_fp8_f32(a, b, (int)old, HI);
#elif defined(HAVE_HIP_FP8)
    unsigned int v = (unsigned int)__hip_fp8_e4m3(a).__x |
                     ((unsigned int)__hip_fp8_e4m3(b).__x << 8);
    return HI ? ((old & 0x0000FFFFu) | (v << 16))
              : ((old & 0xFFFF0000u) | v);
#else
#error "no fp8 conversion path available"
#endif
}

__device__ __forceinline__ unsigned char f2fp8b(float a) {
    return (unsigned char)(pk2_fp8<false>(a, 0.f, 0u) & 0xFFu);
}

// ---------- per-block dtype detect (first 1024 bf16 slots of x) ----------
__device__ __forceinline__ int block_detect_bf16(const void* x, float* sred) {
    const bf16* xb = (const bf16*)x;
    float mx = 0.f;
    for (int t = threadIdx.x; t < 1024; t += blockDim.x) {
        float a = fabsf(__bfloat162float(xb[t]));
        if (!(a < 1e30f)) a = 1e30f;   // NaN/Inf clamp
        mx = fmaxf(mx, a);
    }
#pragma unroll
    for (int off = 32; off; off >>= 1) mx = fmaxf(mx, __shfl_xor(mx, off));
    const int nw = blockDim.x >> 6;
    if ((threadIdx.x & 63) == 0) sred[threadIdx.x >> 6] = mx;
    __syncthreads();
    float m = 0.f;
    for (int wv = 0; wv < nw; ++wv) m = fmaxf(m, sred[wv]);
    return m < 1000.f ? 1 : 0;
}

// ---------- kernel 1: projections (4-way c-split, R11) ----------
// qT/kT: j-major bf16 [b][n][d] (16B rows, MFMA-frag ready).
// vfrag (fp8 e4m3): fragment-major V. Tile = (jblk=j>>5, cs=c>>4),
// 512 BYTES: in-tile byte = ((j>>3)&3)*128 + (c&15)*8 + (j&7); attn A-frag
// load = tile*512 + lane*8 (8B/lane dwordx2, coalesced 512B/instr).
template <typename TIO>
__device__ __forceinline__ void proj_body(
    const TIO* __restrict__ x,
    const TIO* __restrict__ Wq, const TIO* __restrict__ bq,
    const TIO* __restrict__ Wk, const TIO* __restrict__ bk,
    const TIO* __restrict__ Wv, const TIO* __restrict__ bv,
    unsigned short* __restrict__ qT, unsigned short* __restrict__ kT,
    unsigned char* __restrict__ vfrag, float* sW, float* sb, float* part)
{
    const int tid  = threadIdx.x;
    const int colq = tid & 63;                   // column within block
    const int cq   = tid >> 6;                   // c-quarter (wave) 0..3
    const int col  = blockIdx.x * 64 + colq;     // 0..B*NN-1
    const int b    = col >> 12;
    const int n    = col & (NN - 1);
    const int og   = blockIdx.y;                 // 0 => q+k, 1..4 => v

    if (og == 0) {
        for (int t = tid; t < 1024; t += 256) {
            int r = t >> 6, c = t & 63;
            sW[t] = cvt_in<TIO>(r < 8 ? Wq[r * 64 + c] : Wk[(r - 8) * 64 + c]);
        }
        if (tid < 16)
            sb[tid] = cvt_in<TIO>(tid < 8 ? bq[tid] : bk[tid - 8]);
    } else {
        const int r0 = (og - 1) * 16;
        for (int t = tid; t < 1024; t += 256)
            sW[t] = cvt_in<TIO>(Wv[(r0 + (t >> 6)) * 64 + (t & 63)]);
        if (tid < 16)
            sb[tid] = cvt_in<TIO>(bv[r0 + tid]);
    }
    __syncthreads();

    float xv[16];
    const TIO* xb = x + ((size_t)b * CC + cq * 16) * NN + n;
#pragma unroll
    for (int c = 0; c < 16; ++c) xv[c] = cvt_in<TIO>(xb[(size_t)c * NN]);

    float acc[16];
#pragma unroll
    for (int o = 0; o < 16; ++o) {
        float a = 0.f;
#pragma unroll
        for (int c = 0; c < 16; ++c)
            a = fmaf(sW[o * 64 + cq * 16 + c], xv[c], a);
        acc[o] = a;
    }

    if (cq > 0) {
#pragma unroll
        for (int o = 0; o < 16; ++o)
            part[((cq - 1) * 16 + o) * 64 + colq] = acc[o];
    }
    __syncthreads();
    if (cq != 0) return;

#pragma unroll
    for (int o = 0; o < 16; ++o)
        acc[o] += sb[o] + part[o * 64 + colq] + part[(16 + o) * 64 + colq] +
                  part[(32 + o) * 64 + colq];

    if (og == 0) {
        unsigned short row[16];
#pragma unroll
        for (int o = 0; o < 16; ++o) row[o] = (unsigned short)f2b(acc[o]);
        *(short8*)(qT + (size_t)(b * NN + n) * 8) = *(const short8*)&row[0];
        *(short8*)(kT + (size_t)(b * NN + n) * 8) = *(const short8*)&row[8];
    } else {
        unsigned char* vt = vfrag +
            (size_t)((b * 128 + (n >> 5)) * 4 + (og - 1)) * 512 +
            ((n >> 3) & 3) * 128 + (n & 7);
#pragma unroll
        for (int o = 0; o < 16; ++o)
            vt[o * 8] = f2fp8b(acc[o]);
    }
}

__global__ __launch_bounds__(256) void proj_kernel(
    const void* x, const void* Wq, const void* bq, const void* Wk,
    const void* bk, const void* Wv, const void* bv,
    unsigned short* qT, unsigned short* kT, unsigned char* vfrag)
{
    __shared__ float sW[16 * 64];
    __shared__ float sb[16];
    __shared__ float part[3 * 16 * 64];
    __shared__ float sred[4];
    const int bf = block_detect_bf16(x, sred);
    __syncthreads();
    if (bf)
        proj_body<bf16>((const bf16*)x, (const bf16*)Wq, (const bf16*)bq,
                        (const bf16*)Wk, (const bf16*)bk, (const bf16*)Wv,
                        (const bf16*)bv, qT, kT, vfrag, sW, sb, part);
    else
        proj_body<float>((const float*)x, (const float*)Wq, (const float*)bq,
                         (const float*)Wk, (const float*)bk, (const float*)Wv,
                         (const float*)bv, qT, kT, vfrag, sW, sb, part);
}

// ---------- kernel 2: fused flash attention — shuffle-free + fp8 PV ----------
// R16 = R14 verbatim (best measured: 92.5 us total). Single-buffered:
// R15's 2-deep register double-buffer overflowed the (1024,8) 64-VGPR cap
// (WRITE_SIZE 100 MB scratch spills, 129 us) — at this cap there is NO
// headroom for any prefetch depth (also R6/R9). Structure:
// Block = 1024 thr = 16 waves, one block per 16 queries, grid 512,
// launch_bounds (1024,8): 2 blocks/CU, one residency round. kf rows
// j-PERMUTED (R12): S^T MFMA #1 row r ↦ j=(r>>2)*8+(r&3), #2 ↦ +4, so
// lane(q,m)'s 8 exp'd S values are exactly the K=32 B-frag layout
// (k=q*8+e) — zero cross-lane ops. PV runs fp8_fp8 (V pre-quantized e4m3
// in proj, P packed e4m3 here): halves V bytes through L1.
__global__ __launch_bounds__(1024, 8) void attn_kernel(
    const unsigned short* __restrict__ qT, const unsigned short* __restrict__ kT,
    const unsigned char* __restrict__ vfrag,
    const void* __restrict__ xv, const void* __restrict__ gammav, void* outv)
{
    __shared__ float redpool[WV * 1024];   // 64 KB cross-wave acc reduce
    __shared__ float lpart[WV][16];
    __shared__ float sred[WV];

    const int bf = block_detect_bf16(xv, sred);

    const int w    = threadIdx.x >> 6;
    const int lane = threadIdx.x & 63;
    const int m    = lane & 15;
    const int quad = lane >> 4;
    const int b    = blockIdx.x >> 8;
    const int i0   = (blockIdx.x & 255) << 4;

    const short8  zero8 = {};
    const float4v zero4 = {0.f, 0.f, 0.f, 0.f};

    short8 qf = zero8;
    if (quad == 0)
        qf = *(const short8*)(qT + (size_t)(b * NN + i0 + m) * 8);

    float4v acc[4] = {zero4, zero4, zero4, zero4};
    float lsum = 0.f;

    const unsigned short* kTb = kT + (size_t)b * NN * 8;
    const unsigned char*  vfb = vfrag + (size_t)b * CC * NN;

    // permuted j for S rows: row r -> j = (r>>2)*8 + (r&3)
    const int jperm = ((m >> 2) << 3) + (m & 3);
    const int jbase = w * (NN / WV);

#pragma unroll 2
    for (int u = 0; u < 8; ++u) {
        const int j0 = jbase + u * 32;

        short8 kf1 = zero8, kf2 = zero8;
        if (quad == 0) {
            const unsigned short* kp = kTb + (size_t)(j0 + jperm) * 8;
            kf1 = *(const short8*)kp;          // rows -> j = q*8 + r
            kf2 = *(const short8*)(kp + 32);   // rows -> j = q*8 + 4 + r
        }
        const unsigned char* vt = vfb + (size_t)(j0 >> 5) * 4 * 512 + lane * 8;
        const uint2v vf0 = *(const uint2v*)(vt);
        const uint2v vf1 = *(const uint2v*)(vt + 512);

        const float4v st1 =
            __builtin_amdgcn_mfma_f32_16x16x32_bf16(kf1, qf, zero4, 0, 0, 0);
        const float4v st2 =
            __builtin_amdgcn_mfma_f32_16x16x32_bf16(kf2, qf, zero4, 0, 0, 0);

        const float e0 = __expf(st1[0]), e1 = __expf(st1[1]);
        const float e2 = __expf(st1[2]), e3 = __expf(st1[3]);
        const float f0 = __expf(st2[0]), f1 = __expf(st2[1]);
        const float f2 = __expf(st2[2]), f3 = __expf(st2[3]);
        lsum += ((e0 + e1) + (e2 + e3)) + ((f0 + f1) + (f2 + f3));

        // B-frag fp8: byte e ↔ k = q*8+e: [e0..e3, f0..f3]
        uint2v pw;
        pw.x = pk2_fp8<true>(e2, e3, pk2_fp8<false>(e0, e1, 0u));
        pw.y = pk2_fp8<true>(f2, f3, pk2_fp8<false>(f0, f1, 0u));
        const long long pb = __builtin_bit_cast(long long, pw);

        acc[0] = __builtin_amdgcn_mfma_f32_16x16x32_fp8_fp8(
            __builtin_bit_cast(long long, vf0), pb, acc[0], 0, 0, 0);
        const uint2v vf2 = *(const uint2v*)(vt + 1024);
        acc[1] = __builtin_amdgcn_mfma_f32_16x16x32_fp8_fp8(
            __builtin_bit_cast(long long, vf1), pb, acc[1], 0, 0, 0);
        const uint2v vf3 = *(const uint2v*)(vt + 1536);
        acc[2] = __builtin_amdgcn_mfma_f32_16x16x32_fp8_fp8(
            __builtin_bit_cast(long long, vf2), pb, acc[2], 0, 0, 0);
        acc[3] = __builtin_amdgcn_mfma_f32_16x16x32_fp8_fp8(
            __builtin_bit_cast(long long, vf3), pb, acc[3], 0, 0, 0);
    }

    // ---- rowsum: lane's partial covers i=m; reduce across quads ----
    lsum += __shfl_xor(lsum, 16);
    lsum += __shfl_xor(lsum, 32);
    if (lane < 16) lpart[w][lane] = lsum;

    // ---- partial accs -> LDS ----
    float* redw = redpool + w * 1024;
#pragma unroll
    for (int cs = 0; cs < 4; ++cs)
#pragma unroll
        for (int r = 0; r < 4; ++r)
            redw[(cs * 4 + r) * 64 + lane] = acc[cs][r];
    __syncthreads();

    // ---- wave w finalizes t = w: c = (t>>2)*16 + quad*4 + (t&3), i = i0+m ----
    float lt = 0.f;
#pragma unroll
    for (int wv = 0; wv < WV; ++wv) lt += lpart[wv][m];
    const float linv = 1.f / lt;

    float v = 0.f;
#pragma unroll
    for (int wv = 0; wv < WV; ++wv) v += redpool[wv * 1024 + w * 64 + lane];

    const int c  = (w >> 2) * 16 + quad * 4 + (w & 3);
    const int ig = i0 + m;
    const size_t off = ((size_t)b * CC + c) * NN + ig;

    if (bf) {
        const float gl = __bfloat162float(((const bf16*)gammav)[0]) * linv;
        ((bf16*)outv)[off] = __float2bfloat16(
            fmaf(gl, v, __bfloat162float(((const bf16*)xv)[off])));
    } else {
        const float gl = ((const float*)gammav)[0] * linv;
        ((float*)outv)[off] = fmaf(gl, v, ((const float*)xv)[off]);
    }
}

extern "C" void kernel_launch(void* const* d_in, const int* in_sizes, int n_in,
                              void* d_out, int out_size, void* d_ws, size_t ws_size,
                              hipStream_t stream)
{
    const void* x     = d_in[0];
    const void* Wq    = d_in[1];
    const void* bq    = d_in[2];
    const void* Wk    = d_in[3];
    const void* bk    = d_in[4];
    const void* Wv    = d_in[5];
    const void* bv    = d_in[6];
    const void* gamma = d_in[7];

    // workspace: qT | kT (bf16-as-ushort) | vfrag (fp8 bytes)
    unsigned short* qT    = (unsigned short*)d_ws;
    unsigned short* kT    = qT + (size_t)BB * NN * 8;
    unsigned char*  vfrag = (unsigned char*)(kT + (size_t)BB * NN * 8);

    proj_kernel<<<dim3(BB * NN / 64, 5), 256, 0, stream>>>(
        x, Wq, bq, Wk, bk, Wv, bv, qT, kT, vfrag);
    attn_kernel<<<BB * (NN / 16), 1024, 0, stream>>>(
        qT, kT, vfrag, x, gamma, d_out);
}